// Round 1
// baseline (369.853 us; speedup 1.0000x reference)
//
#include <hip/hip_runtime.h>
#include <math.h>

#define Bdim  2
#define Nseq  2048
#define Dmod  512
#define Hn    8
#define DHd   64
#define HID   2730
#define HHALF 1365
#define HPAD  1376
#define ROWS  4096   // Bdim*Nseq

typedef __bf16 bf16x8 __attribute__((ext_vector_type(8)));
typedef float  f32x4  __attribute__((ext_vector_type(4)));

// ---------------- fp32 -> bf16 convert with optional column pad (zeros) ----------------
__global__ __launch_bounds__(256) void convert_pad_kernel(
    const float* __restrict__ in, __bf16* __restrict__ out,
    int rows, int cols, int ldout, int total)
{
    int idx = blockIdx.x * 256 + threadIdx.x;
    if (idx >= total) return;
    int r = idx / ldout, c = idx - r * ldout;
    float v = (c < cols) ? in[(size_t)r * cols + c] : 0.0f;
    out[idx] = (__bf16)v;
}

// ---------------- LayerNorm fp32 -> bf16 (row = 512) ----------------
__global__ __launch_bounds__(256) void ln_kernel(
    const float* __restrict__ x, const float* __restrict__ w,
    const float* __restrict__ b, __bf16* __restrict__ out)
{
    const int row = blockIdx.x;
    const int tid = threadIdx.x;
    const float* xr = x + (size_t)row * Dmod;
    float2 v = *(const float2*)(xr + tid * 2);
    float s  = v.x + v.y;
    float sq = v.x * v.x + v.y * v.y;
#pragma unroll
    for (int m = 1; m < 64; m <<= 1) {
        s  += __shfl_xor(s, m, 64);
        sq += __shfl_xor(sq, m, 64);
    }
    __shared__ float ss[4], ssq[4];
    const int wv = tid >> 6;
    if ((tid & 63) == 0) { ss[wv] = s; ssq[wv] = sq; }
    __syncthreads();
    s  = ss[0] + ss[1] + ss[2] + ss[3];
    sq = ssq[0] + ssq[1] + ssq[2] + ssq[3];
    const float mean = s * (1.0f / Dmod);
    const float var  = sq * (1.0f / Dmod) - mean * mean;
    const float rstd = rsqrtf(var + 1e-5f);
    float2 wv2 = *(const float2*)(w + tid * 2);
    float2 bv2 = *(const float2*)(b + tid * 2);
    __bf16* orow = out + (size_t)row * Dmod + tid * 2;
    orow[0] = (__bf16)((v.x - mean) * rstd * wv2.x + bv2.x);
    orow[1] = (__bf16)((v.y - mean) * rstd * wv2.y + bv2.y);
}

// ---------------- GEMM: C[M,N] = A[M,K] * B[N,K]^T + bias ----------------
// A,B bf16 row-major. M%64==0, K%32==0, lda/ldb multiples of 8.
// MODE 0: out_bf[m,n] = (__bf16)(acc+bias)
// MODE 1: out_f32[m,n] = res[m,n] + g[n]*(acc+bias)
template<int MODE>
__global__ __launch_bounds__(256) void gemm_bt(
    const __bf16* __restrict__ A, int lda,
    const __bf16* __restrict__ Bw, int ldb,
    const float* __restrict__ bias,
    int N, int K,
    __bf16* __restrict__ out_bf, int ld_out,
    float* __restrict__ out_f32,
    const float* __restrict__ res,
    const float* __restrict__ g)
{
    __shared__ __bf16 As[64][40];    // 64x32 tile, +8 pad (80B row, 16B aligned)
    __shared__ __bf16 Bs[128][40];
    const int tid  = threadIdx.x;
    const int wave = tid >> 6, lane = tid & 63;
    const int t    = lane & 15, quad = lane >> 4;
    const int m0   = blockIdx.x * 64;
    const int n0   = blockIdx.y * 128;

    f32x4 acc[8] = {};
    const int sr = tid >> 2, sc = (tid & 3) * 8;   // A staging: row, col-chunk

    for (int k0 = 0; k0 < K; k0 += 32) {
        bf16x8 av = *(const bf16x8*)(A + (size_t)(m0 + sr) * lda + (k0 + sc));
        bf16x8 bv[2];
#pragma unroll
        for (int i = 0; i < 2; ++i) {
            int c = tid + i * 256;
            int r = c >> 2, cc = (c & 3) * 8;
            int row = n0 + r;
            bf16x8 z = {};
            bv[i] = z;
            if (row < N) bv[i] = *(const bf16x8*)(Bw + (size_t)row * ldb + (k0 + cc));
        }
        __syncthreads();   // protect LDS from previous iteration's readers
        *(bf16x8*)(&As[sr][sc]) = av;
#pragma unroll
        for (int i = 0; i < 2; ++i) {
            int c = tid + i * 256;
            int r = c >> 2, cc = (c & 3) * 8;
            *(bf16x8*)(&Bs[r][cc]) = bv[i];
        }
        __syncthreads();
        bf16x8 a = *(const bf16x8*)(&As[wave * 16 + t][quad * 8]);
#pragma unroll
        for (int ct = 0; ct < 8; ++ct) {
            bf16x8 b = *(const bf16x8*)(&Bs[ct * 16 + t][quad * 8]);
            acc[ct] = __builtin_amdgcn_mfma_f32_16x16x32_bf16(a, b, acc[ct], 0, 0, 0);
        }
    }

    // epilogue: C/D layout col=lane&15, row=quad*4+reg  [verified m89/m91]
    const int row_base = m0 + wave * 16 + quad * 4;
#pragma unroll
    for (int ct = 0; ct < 8; ++ct) {
        const int col = n0 + ct * 16 + t;
        if (col >= N) continue;
        const float bb = bias[col];
#pragma unroll
        for (int r = 0; r < 4; ++r) {
            const int row = row_base + r;
            float v = acc[ct][r] + bb;
            if (MODE == 0) {
                out_bf[(size_t)row * ld_out + col] = (__bf16)v;
            } else {
                out_f32[(size_t)row * ld_out + col] =
                    res[(size_t)row * ld_out + col] + g[col] * v;
            }
        }
    }
}

// ---------------- Flash attention with distance-ALiBi bias ----------------
// grid: (qtile=Nseq/64, Hn, Bdim), block 256 (4 waves, 16 q-rows each)
__global__ __launch_bounds__(256) void attn_kernel(
    const __bf16* __restrict__ Q, const __bf16* __restrict__ Kb,
    const __bf16* __restrict__ Vb, const float* __restrict__ coords,
    __bf16* __restrict__ ctx)
{
    constexpr int LD = DHd + 8;    // 72 elems = 144B rows, 16B aligned
    __shared__ __bf16 Qs[64][LD];
    __shared__ __bf16 Ks[64][LD];
    __shared__ __bf16 Vt[64][LD];  // Vt[dh][key]
    __shared__ __bf16 Ps[64][LD];
    __shared__ float  kcx[64], kcy[64];

    const int qt = blockIdx.x, h = blockIdx.y, b = blockIdx.z;
    const int tid = threadIdx.x;
    const int wave = tid >> 6, lane = tid & 63;
    const int t = lane & 15, quad = lane >> 4;
    const float slope = exp2f(-(float)(h + 1));   // slopes[h] = 0.5^(h+1)
    const float scale = 0.125f;                   // 1/sqrt(64)

    // stage Q tile [64][64]
    const int sr = tid >> 2, sc = (tid & 3) * 8;  // covers cols 0..31; need 2 chunks
    {
        const size_t baseQ = ((size_t)b * Nseq + qt * 64) * Dmod + h * DHd;
#pragma unroll
        for (int i = 0; i < 2; ++i) {
            int cc = sc + i * 32;
            *(bf16x8*)(&Qs[sr][cc]) = *(const bf16x8*)(Q + baseQ + (size_t)sr * Dmod + cc);
        }
    }
    // q coords for this lane's 4 rows
    float qx[4], qy[4];
    const int qrow_base = qt * 64 + wave * 16 + quad * 4;
#pragma unroll
    for (int r = 0; r < 4; ++r) {
        float2 c = *(const float2*)(coords + ((size_t)b * Nseq + qrow_base + r) * 2);
        qx[r] = c.x; qy[r] = c.y;
    }
    __syncthreads();
    bf16x8 aq0 = *(const bf16x8*)(&Qs[wave * 16 + t][quad * 8]);
    bf16x8 aq1 = *(const bf16x8*)(&Qs[wave * 16 + t][32 + quad * 8]);

    f32x4 o[4] = {};
    float mrow[4], lrow[4];
#pragma unroll
    for (int r = 0; r < 4; ++r) { mrow[r] = -1e30f; lrow[r] = 0.0f; }

    for (int kt = 0; kt < Nseq / 64; ++kt) {
        __syncthreads();   // prev iter's consumers of Ks/Vt/kc done
        const size_t baseK = ((size_t)b * Nseq + kt * 64) * Dmod + h * DHd;
        // stage K tile [64 keys][64 dh]
#pragma unroll
        for (int i = 0; i < 2; ++i) {
            int c = tid + i * 256;           // 512 chunks of 8
            int r = c >> 3, cc = (c & 7) * 8;
            *(bf16x8*)(&Ks[r][cc]) = *(const bf16x8*)(Kb + baseK + (size_t)r * Dmod + cc);
        }
        // stage V transposed: Vt[dh][key]
#pragma unroll
        for (int i = 0; i < 2; ++i) {
            int c = tid + i * 256;
            int r = c >> 3, cc = (c & 7) * 8;
            bf16x8 vv = *(const bf16x8*)(Vb + baseK + (size_t)r * Dmod + cc);
#pragma unroll
            for (int j = 0; j < 8; ++j) Vt[cc + j][r] = vv[j];
        }
        if (tid < 64) {
            float2 c = *(const float2*)(coords + ((size_t)b * Nseq + kt * 64 + tid) * 2);
            kcx[tid] = c.x; kcy[tid] = c.y;
        }
        __syncthreads();

        // S = Q K^T  (16 q-rows x 64 keys per wave)
        f32x4 s[4] = {};
#pragma unroll
        for (int ct = 0; ct < 4; ++ct) {
            bf16x8 b0 = *(const bf16x8*)(&Ks[ct * 16 + t][quad * 8]);
            bf16x8 b1 = *(const bf16x8*)(&Ks[ct * 16 + t][32 + quad * 8]);
            s[ct] = __builtin_amdgcn_mfma_f32_16x16x32_bf16(aq0, b0, s[ct], 0, 0, 0);
            s[ct] = __builtin_amdgcn_mfma_f32_16x16x32_bf16(aq1, b1, s[ct], 0, 0, 0);
        }
        // scores + distance bias (fp32)
        float sv[4][4];
#pragma unroll
        for (int ct = 0; ct < 4; ++ct) {
            const int key = ct * 16 + t;
            const float kx = kcx[key], ky = kcy[key];
#pragma unroll
            for (int r = 0; r < 4; ++r) {
                float dx = qx[r] - kx, dy = qy[r] - ky;
                sv[ct][r] = s[ct][r] * scale - slope * sqrtf(dx * dx + dy * dy);
            }
        }
        // online softmax per q-row (reduce across the 16 lanes of this quad-group)
        float mnew[4], alpha[4];
#pragma unroll
        for (int r = 0; r < 4; ++r) {
            float mx = fmaxf(fmaxf(sv[0][r], sv[1][r]), fmaxf(sv[2][r], sv[3][r]));
#pragma unroll
            for (int msk = 1; msk < 16; msk <<= 1) mx = fmaxf(mx, __shfl_xor(mx, msk, 64));
            mnew[r]  = fmaxf(mrow[r], mx);
            alpha[r] = __expf(mrow[r] - mnew[r]);
            mrow[r]  = mnew[r];
        }
        float rsum[4] = {0.f, 0.f, 0.f, 0.f};
#pragma unroll
        for (int ct = 0; ct < 4; ++ct)
#pragma unroll
            for (int r = 0; r < 4; ++r) {
                float p = __expf(sv[ct][r] - mnew[r]);
                sv[ct][r] = p;
                rsum[r] += p;
            }
#pragma unroll
        for (int r = 0; r < 4; ++r) {
#pragma unroll
            for (int msk = 1; msk < 16; msk <<= 1) rsum[r] += __shfl_xor(rsum[r], msk, 64);
            lrow[r] = lrow[r] * alpha[r] + rsum[r];
        }
#pragma unroll
        for (int ct = 0; ct < 4; ++ct)
#pragma unroll
            for (int r = 0; r < 4; ++r) o[ct][r] *= alpha[r];

        // P: C/D layout -> LDS -> A layout  [verified round-trip, m120]
#pragma unroll
        for (int ct = 0; ct < 4; ++ct)
#pragma unroll
            for (int r = 0; r < 4; ++r)
                Ps[wave * 16 + quad * 4 + r][ct * 16 + t] = (__bf16)sv[ct][r];
        __syncthreads();

        // O += P * V
        bf16x8 ap0 = *(const bf16x8*)(&Ps[wave * 16 + t][quad * 8]);
        bf16x8 ap1 = *(const bf16x8*)(&Ps[wave * 16 + t][32 + quad * 8]);
#pragma unroll
        for (int ct = 0; ct < 4; ++ct) {
            bf16x8 bv0 = *(const bf16x8*)(&Vt[ct * 16 + t][quad * 8]);
            bf16x8 bv1 = *(const bf16x8*)(&Vt[ct * 16 + t][32 + quad * 8]);
            o[ct] = __builtin_amdgcn_mfma_f32_16x16x32_bf16(ap0, bv0, o[ct], 0, 0, 0);
            o[ct] = __builtin_amdgcn_mfma_f32_16x16x32_bf16(ap1, bv1, o[ct], 0, 0, 0);
        }
    }

    // epilogue: ctx[b, qrow, h, dh] = o / l
#pragma unroll
    for (int ct = 0; ct < 4; ++ct) {
#pragma unroll
        for (int r = 0; r < 4; ++r) {
            float val = o[ct][r] / lrow[r];
            size_t row = (size_t)b * Nseq + qt * 64 + wave * 16 + quad * 4 + r;
            ctx[row * Dmod + h * DHd + ct * 16 + t] = (__bf16)val;
        }
    }
}

// ---------------- SwiGLU: h = silu(h1) * h2, padded to HPAD with zeros ----------------
__global__ __launch_bounds__(256) void swiglu_kernel(
    const __bf16* __restrict__ hpre, __bf16* __restrict__ out)
{
    int idx = blockIdx.x * 256 + threadIdx.x;
    if (idx >= ROWS * HPAD) return;
    int r = idx / HPAD, c = idx - r * HPAD;
    float v = 0.0f;
    if (c < HHALF) {
        float a  = (float)hpre[(size_t)r * HID + c];
        float b2 = (float)hpre[(size_t)r * HID + HHALF + c];
        v = a / (1.0f + __expf(-a)) * b2;
    }
    out[idx] = (__bf16)v;
}

// ---------------- launch ----------------
extern "C" void kernel_launch(void* const* d_in, const int* in_sizes, int n_in,
                              void* d_out, int out_size, void* d_ws, size_t ws_size,
                              hipStream_t stream)
{
    (void)in_sizes; (void)n_in; (void)out_size; (void)ws_size;
    const float* x      = (const float*)d_in[0];
    const float* coords = (const float*)d_in[1];
    const float* q_w    = (const float*)d_in[2];
    const float* q_b    = (const float*)d_in[3];
    const float* k_w    = (const float*)d_in[4];
    const float* k_b    = (const float*)d_in[5];
    const float* v_w    = (const float*)d_in[6];
    const float* v_b    = (const float*)d_in[7];
    const float* o_w    = (const float*)d_in[8];
    const float* o_b    = (const float*)d_in[9];
    const float* gamma1 = (const float*)d_in[10];
    const float* ln1_w  = (const float*)d_in[11];
    const float* ln1_b  = (const float*)d_in[12];
    const float* fc1_w  = (const float*)d_in[13];
    const float* fc1_b  = (const float*)d_in[14];
    const float* fc2_w  = (const float*)d_in[15];
    const float* fc2_b  = (const float*)d_in[16];
    const float* gamma2 = (const float*)d_in[17];
    const float* ln2_w  = (const float*)d_in[18];
    const float* ln2_b  = (const float*)d_in[19];

    size_t off = 0;
    auto alloc = [&](size_t bytes) {
        void* p = (char*)d_ws + off;
        off += (bytes + 255) & ~(size_t)255;
        return p;
    };
    __bf16* xn    = (__bf16*)alloc((size_t)ROWS * Dmod * 2);
    __bf16* xn2   = (__bf16*)alloc((size_t)ROWS * Dmod * 2);
    __bf16* wq    = (__bf16*)alloc((size_t)Dmod * Dmod * 2);
    __bf16* wk    = (__bf16*)alloc((size_t)Dmod * Dmod * 2);
    __bf16* wv    = (__bf16*)alloc((size_t)Dmod * Dmod * 2);
    __bf16* wo    = (__bf16*)alloc((size_t)Dmod * Dmod * 2);
    __bf16* wfc1  = (__bf16*)alloc((size_t)HID * Dmod * 2);
    __bf16* wfc2  = (__bf16*)alloc((size_t)Dmod * HPAD * 2);
    __bf16* qb    = (__bf16*)alloc((size_t)ROWS * Dmod * 2);
    __bf16* kb    = (__bf16*)alloc((size_t)ROWS * Dmod * 2);
    __bf16* vb    = (__bf16*)alloc((size_t)ROWS * Dmod * 2);
    __bf16* ctxb  = (__bf16*)alloc((size_t)ROWS * Dmod * 2);
    float*  x1    = (float*)alloc((size_t)ROWS * Dmod * 4);
    __bf16* hpre  = (__bf16*)alloc((size_t)ROWS * HID * 2);
    __bf16* hcomb = (__bf16*)alloc((size_t)ROWS * HPAD * 2);

    // weight conversions
    convert_pad_kernel<<<(Dmod * Dmod + 255) / 256, 256, 0, stream>>>(q_w, wq, Dmod, Dmod, Dmod, Dmod * Dmod);
    convert_pad_kernel<<<(Dmod * Dmod + 255) / 256, 256, 0, stream>>>(k_w, wk, Dmod, Dmod, Dmod, Dmod * Dmod);
    convert_pad_kernel<<<(Dmod * Dmod + 255) / 256, 256, 0, stream>>>(v_w, wv, Dmod, Dmod, Dmod, Dmod * Dmod);
    convert_pad_kernel<<<(Dmod * Dmod + 255) / 256, 256, 0, stream>>>(o_w, wo, Dmod, Dmod, Dmod, Dmod * Dmod);
    convert_pad_kernel<<<(HID * Dmod + 255) / 256, 256, 0, stream>>>(fc1_w, wfc1, HID, Dmod, Dmod, HID * Dmod);
    convert_pad_kernel<<<(Dmod * HPAD + 255) / 256, 256, 0, stream>>>(fc2_w, wfc2, Dmod, HHALF, HPAD, Dmod * HPAD);

    // LN1
    ln_kernel<<<ROWS, 256, 0, stream>>>(x, ln1_w, ln1_b, xn);

    // QKV projections
    gemm_bt<0><<<dim3(ROWS / 64, 4), 256, 0, stream>>>(xn, Dmod, wq, Dmod, q_b, Dmod, Dmod, qb, Dmod, nullptr, nullptr, nullptr);
    gemm_bt<0><<<dim3(ROWS / 64, 4), 256, 0, stream>>>(xn, Dmod, wk, Dmod, k_b, Dmod, Dmod, kb, Dmod, nullptr, nullptr, nullptr);
    gemm_bt<0><<<dim3(ROWS / 64, 4), 256, 0, stream>>>(xn, Dmod, wv, Dmod, v_b, Dmod, Dmod, vb, Dmod, nullptr, nullptr, nullptr);

    // attention
    attn_kernel<<<dim3(Nseq / 64, Hn, Bdim), 256, 0, stream>>>(qb, kb, vb, coords, ctxb);

    // O projection + residual1 -> x1 (fp32)
    gemm_bt<1><<<dim3(ROWS / 64, 4), 256, 0, stream>>>(ctxb, Dmod, wo, Dmod, o_b, Dmod, Dmod, nullptr, Dmod, x1, x, gamma1);

    // LN2
    ln_kernel<<<ROWS, 256, 0, stream>>>(x1, ln2_w, ln2_b, xn2);

    // fc1 -> hpre (bf16, ld = HID, N-guarded)
    gemm_bt<0><<<dim3(ROWS / 64, (HID + 127) / 128), 256, 0, stream>>>(xn2, Dmod, wfc1, Dmod, fc1_b, HID, Dmod, hpre, HID, nullptr, nullptr, nullptr);

    // SwiGLU -> hcomb (padded K)
    swiglu_kernel<<<(ROWS * HPAD + 255) / 256, 256, 0, stream>>>(hpre, hcomb);

    // fc2 + residual2 -> d_out (fp32)
    gemm_bt<1><<<dim3(ROWS / 64, 4), 256, 0, stream>>>(hcomb, HPAD, wfc2, HPAD, fc2_b, Dmod, HPAD, nullptr, Dmod, (float*)d_out, x1, gamma2);
}

// Round 3
// 309.188 us; speedup vs baseline: 1.1962x; 1.1962x over previous
//
#include <hip/hip_runtime.h>
#include <math.h>

#define Bdim  2
#define Nseq  2048
#define Dmod  512
#define Hn    8
#define DHd   64
#define HID   2730
#define HHALF 1365
#define HPAD  1376
#define ROWS  4096   // Bdim*Nseq

typedef __bf16 bf16x8 __attribute__((ext_vector_type(8)));
typedef __bf16 bf16x4 __attribute__((ext_vector_type(4)));
typedef float  f32x4  __attribute__((ext_vector_type(4)));

// ---------------- fp32 -> bf16 convert with optional column pad (zeros) ----------------
__global__ __launch_bounds__(256) void convert_pad_kernel(
    const float* __restrict__ in, __bf16* __restrict__ out,
    int rows, int cols, int ldout, int total)
{
    int idx = blockIdx.x * 256 + threadIdx.x;
    if (idx >= total) return;
    int r = idx / ldout, c = idx - r * ldout;
    float v = (c < cols) ? in[(size_t)r * cols + c] : 0.0f;
    out[idx] = (__bf16)v;
}

// ---------------- LayerNorm fp32 -> bf16 (row = 512) ----------------
__global__ __launch_bounds__(256) void ln_kernel(
    const float* __restrict__ x, const float* __restrict__ w,
    const float* __restrict__ b, __bf16* __restrict__ out)
{
    const int row = blockIdx.x;
    const int tid = threadIdx.x;
    const float* xr = x + (size_t)row * Dmod;
    float2 v = *(const float2*)(xr + tid * 2);
    float s  = v.x + v.y;
    float sq = v.x * v.x + v.y * v.y;
#pragma unroll
    for (int m = 1; m < 64; m <<= 1) {
        s  += __shfl_xor(s, m, 64);
        sq += __shfl_xor(sq, m, 64);
    }
    __shared__ float ss[4], ssq[4];
    const int wv = tid >> 6;
    if ((tid & 63) == 0) { ss[wv] = s; ssq[wv] = sq; }
    __syncthreads();
    s  = ss[0] + ss[1] + ss[2] + ss[3];
    sq = ssq[0] + ssq[1] + ssq[2] + ssq[3];
    const float mean = s * (1.0f / Dmod);
    const float var  = sq * (1.0f / Dmod) - mean * mean;
    const float rstd = rsqrtf(var + 1e-5f);
    float2 wv2 = *(const float2*)(w + tid * 2);
    float2 bv2 = *(const float2*)(b + tid * 2);
    __bf16* orow = out + (size_t)row * Dmod + tid * 2;
    orow[0] = (__bf16)((v.x - mean) * rstd * wv2.x + bv2.x);
    orow[1] = (__bf16)((v.y - mean) * rstd * wv2.y + bv2.y);
}

// ---------------- GEMM: C[M,N] = A[M,K] * B[N,K]^T + bias ----------------
// MODE 0: out_bf[m,n] = (__bf16)(acc+bias)
// MODE 1: out_f32[m,n] = res[m,n] + g[n]*(acc+bias)
template<int MODE, int NT>
__global__ __launch_bounds__(256) void gemm_bt(
    const __bf16* __restrict__ A, int lda,
    const __bf16* __restrict__ Bw, int ldb,
    const float* __restrict__ bias,
    int N, int K,
    __bf16* __restrict__ out_bf, int ld_out,
    float* __restrict__ out_f32,
    const float* __restrict__ res,
    const float* __restrict__ g)
{
    __shared__ __bf16 As[64][40];
    __shared__ __bf16 Bs[NT][40];
    const int tid  = threadIdx.x;
    const int wave = tid >> 6, lane = tid & 63;
    const int t    = lane & 15, quad = lane >> 4;
    const int m0   = blockIdx.x * 64;
    const int n0   = blockIdx.y * NT;

    f32x4 acc[NT / 16] = {};
    const int sr = tid >> 2, sc = (tid & 3) * 8;

    for (int k0 = 0; k0 < K; k0 += 32) {
        bf16x8 av = *(const bf16x8*)(A + (size_t)(m0 + sr) * lda + (k0 + sc));
        bf16x8 bv[NT / 64];
#pragma unroll
        for (int i = 0; i < NT / 64; ++i) {
            int c = tid + i * 256;
            int r = c >> 2, cc = (c & 3) * 8;
            int row = n0 + r;
            bf16x8 z = {};
            bv[i] = z;
            if (row < N) bv[i] = *(const bf16x8*)(Bw + (size_t)row * ldb + (k0 + cc));
        }
        __syncthreads();
        *(bf16x8*)(&As[sr][sc]) = av;
#pragma unroll
        for (int i = 0; i < NT / 64; ++i) {
            int c = tid + i * 256;
            int r = c >> 2, cc = (c & 3) * 8;
            *(bf16x8*)(&Bs[r][cc]) = bv[i];
        }
        __syncthreads();
        bf16x8 a = *(const bf16x8*)(&As[wave * 16 + t][quad * 8]);
#pragma unroll
        for (int ct = 0; ct < NT / 16; ++ct) {
            bf16x8 b = *(const bf16x8*)(&Bs[ct * 16 + t][quad * 8]);
            acc[ct] = __builtin_amdgcn_mfma_f32_16x16x32_bf16(a, b, acc[ct], 0, 0, 0);
        }
    }

    const int row_base = m0 + wave * 16 + quad * 4;
#pragma unroll
    for (int ct = 0; ct < NT / 16; ++ct) {
        const int col = n0 + ct * 16 + t;
        if (col >= N) continue;
        const float bb = bias[col];
#pragma unroll
        for (int r = 0; r < 4; ++r) {
            const int row = row_base + r;
            float v = acc[ct][r] + bb;
            if (MODE == 0) {
                out_bf[(size_t)row * ld_out + col] = (__bf16)v;
            } else {
                out_f32[(size_t)row * ld_out + col] =
                    res[(size_t)row * ld_out + col] + g[col] * v;
            }
        }
    }
}

// ---------------- Fused QKV GEMM: N=1536; V third written transposed ----------------
// qk[token][0:1024] = q|k ; vt[(b*8+h)*64+dh][n] = v
__global__ __launch_bounds__(256) void qkv_gemm(
    const __bf16* __restrict__ A, const __bf16* __restrict__ W,
    const float* __restrict__ qb_, const float* __restrict__ kb_,
    const float* __restrict__ vb_,
    __bf16* __restrict__ qk, __bf16* __restrict__ vt)
{
    __shared__ __bf16 As[64][40];
    __shared__ __bf16 Bs[128][40];
    const int tid  = threadIdx.x;
    const int wave = tid >> 6, lane = tid & 63;
    const int t    = lane & 15, quad = lane >> 4;
    const int m0   = blockIdx.x * 64;
    const int n0   = blockIdx.y * 128;

    f32x4 acc[8] = {};
    const int sr = tid >> 2, sc = (tid & 3) * 8;

    for (int k0 = 0; k0 < Dmod; k0 += 32) {
        bf16x8 av = *(const bf16x8*)(A + (size_t)(m0 + sr) * Dmod + (k0 + sc));
        bf16x8 bv[2];
#pragma unroll
        for (int i = 0; i < 2; ++i) {
            int c = tid + i * 256;
            int r = c >> 2, cc = (c & 3) * 8;
            bv[i] = *(const bf16x8*)(W + (size_t)(n0 + r) * Dmod + (k0 + cc));
        }
        __syncthreads();
        *(bf16x8*)(&As[sr][sc]) = av;
#pragma unroll
        for (int i = 0; i < 2; ++i) {
            int c = tid + i * 256;
            int r = c >> 2, cc = (c & 3) * 8;
            *(bf16x8*)(&Bs[r][cc]) = bv[i];
        }
        __syncthreads();
        bf16x8 a = *(const bf16x8*)(&As[wave * 16 + t][quad * 8]);
#pragma unroll
        for (int ct = 0; ct < 8; ++ct) {
            bf16x8 b = *(const bf16x8*)(&Bs[ct * 16 + t][quad * 8]);
            acc[ct] = __builtin_amdgcn_mfma_f32_16x16x32_bf16(a, b, acc[ct], 0, 0, 0);
        }
    }

    const int row_base = m0 + wave * 16 + quad * 4;
#pragma unroll
    for (int ct = 0; ct < 8; ++ct) {
        const int col = n0 + ct * 16 + t;
        const float bb = (col < 512) ? qb_[col]
                        : (col < 1024) ? kb_[col - 512] : vb_[col - 1024];
        if (col < 1024) {
#pragma unroll
            for (int r = 0; r < 4; ++r)
                qk[(size_t)(row_base + r) * 1024 + col] = (__bf16)(acc[ct][r] + bb);
        } else {
            const int f = col - 1024, hh = f >> 6, dh = f & 63;
            const int bI = row_base >> 11, n = row_base & 2047;
            bf16x4 pk;
#pragma unroll
            for (int r = 0; r < 4; ++r) pk[r] = (__bf16)(acc[ct][r] + bb);
            *(bf16x4*)(vt + ((size_t)((bI * 8 + hh) * 64 + dh)) * Nseq + n) = pk;
        }
    }
}

// ---------------- Flash attention, S^T formulation ----------------
// grid: (Nseq/64, Hn, Bdim), block 256 (4 waves, 16 q-rows each)
__global__ __launch_bounds__(256) void attn_kernel(
    const __bf16* __restrict__ qk, const __bf16* __restrict__ vt,
    const float* __restrict__ coords, __bf16* __restrict__ ctx)
{
    constexpr int LD = 72;   // 144B rows (144 = 9*16, b128-aligned)
    __shared__ __bf16 Ks[64][LD];
    __shared__ __bf16 Vt[64][LD];   // Vt[dh][key]
    __shared__ __bf16 Ps[64][LD];   // wave-private rows [wave*16+t]
    __shared__ float2 kco[64];

    const int qt = blockIdx.x, h = blockIdx.y, b = blockIdx.z;
    const int bh = b * Hn + h;
    const int tid = threadIdx.x;
    const int wave = tid >> 6, lane = tid & 63;
    const int t = lane & 15, quad = lane >> 4;
    const float slope = exp2f(-(float)(h + 1));
    const float scale = 0.125f;

    // Q fragments direct from global (B-operand: Q[q=t][dh=quad*8+j])
    const int qrow = qt * 64 + wave * 16 + t;
    const size_t qbase = (size_t)(b * Nseq + qrow) * 1024 + h * DHd;
    bf16x8 bq0 = *(const bf16x8*)(qk + qbase + quad * 8);
    bf16x8 bq1 = *(const bf16x8*)(qk + qbase + 32 + quad * 8);
    float2 qc = *(const float2*)(coords + (size_t)(b * Nseq + qrow) * 2);
    const float qx = qc.x, qy = qc.y;

    f32x4 o[4] = {};
    float mrun = -1e30f, lrun = 0.0f;

    for (int kt = 0; kt < Nseq / 64; ++kt) {
        __syncthreads();
        {
            const size_t kb2 = (size_t)(b * Nseq + kt * 64) * 1024 + 512 + h * DHd;
            const size_t vb2 = (size_t)(bh * 64) * Nseq + kt * 64;
#pragma unroll
            for (int i = 0; i < 2; ++i) {
                int c = tid + i * 256;
                int r = c >> 3, cc = (c & 7) * 8;
                *(bf16x8*)(&Ks[r][cc]) = *(const bf16x8*)(qk + kb2 + (size_t)r * 1024 + cc);
                *(bf16x8*)(&Vt[r][cc]) = *(const bf16x8*)(vt + vb2 + (size_t)r * Nseq + cc);
            }
            if (tid < 64)
                kco[tid] = *(const float2*)(coords + (size_t)(b * Nseq + kt * 64 + tid) * 2);
        }
        __syncthreads();

        // S^T = K·Q^T : per am, rows key=am*16+quad*4+r, col q=t
        f32x4 s[4];
#pragma unroll
        for (int am = 0; am < 4; ++am) {
            bf16x8 a0 = *(const bf16x8*)(&Ks[am * 16 + t][quad * 8]);
            bf16x8 a1 = *(const bf16x8*)(&Ks[am * 16 + t][32 + quad * 8]);
            f32x4 z = {};
            z = __builtin_amdgcn_mfma_f32_16x16x32_bf16(a0, bq0, z, 0, 0, 0);
            s[am] = __builtin_amdgcn_mfma_f32_16x16x32_bf16(a1, bq1, z, 0, 0, 0);
        }

        // bias + running max (all 16 scores belong to q=t)
        float p[4][4];
        float mx = -1e30f;
#pragma unroll
        for (int am = 0; am < 4; ++am) {
#pragma unroll
            for (int r = 0; r < 4; ++r) {
                float2 kc = kco[am * 16 + quad * 4 + r];
                float dx = qx - kc.x, dy = qy - kc.y;
                float v = s[am][r] * scale - slope * sqrtf(dx * dx + dy * dy);
                p[am][r] = v;
                mx = fmaxf(mx, v);
            }
        }
        mx = fmaxf(mx, __shfl_xor(mx, 16, 64));
        mx = fmaxf(mx, __shfl_xor(mx, 32, 64));
        const float mnew = fmaxf(mrun, mx);
        const float alpha = __expf(mrun - mnew);
        mrun = mnew;
        float rsum = 0.0f;
#pragma unroll
        for (int am = 0; am < 4; ++am)
#pragma unroll
            for (int r = 0; r < 4; ++r) {
                float pe = __expf(p[am][r] - mnew);
                p[am][r] = pe;
                rsum += pe;
            }
        rsum += __shfl_xor(rsum, 16, 64);
        rsum += __shfl_xor(rsum, 32, 64);
        lrun = lrun * alpha + rsum;

        // P -> LDS (wave-private rows, packed b64; same-wave write->read)
#pragma unroll
        for (int am = 0; am < 4; ++am) {
            bf16x4 pk;
#pragma unroll
            for (int r = 0; r < 4; ++r) pk[r] = (__bf16)p[am][r];
            *(bf16x4*)(&Ps[wave * 16 + t][am * 16 + quad * 4]) = pk;
        }

        // rescale O by alpha (O rows are q=quad*4+r; alpha lives at lane q)
        float alo[4];
#pragma unroll
        for (int r = 0; r < 4; ++r) alo[r] = __shfl(alpha, quad * 4 + r, 64);
#pragma unroll
        for (int ct = 0; ct < 4; ++ct)
#pragma unroll
            for (int r = 0; r < 4; ++r) o[ct][r] *= alo[r];

        bf16x8 ap0 = *(const bf16x8*)(&Ps[wave * 16 + t][quad * 8]);
        bf16x8 ap1 = *(const bf16x8*)(&Ps[wave * 16 + t][32 + quad * 8]);
#pragma unroll
        for (int ct = 0; ct < 4; ++ct) {
            bf16x8 bv0 = *(const bf16x8*)(&Vt[ct * 16 + t][quad * 8]);
            bf16x8 bv1 = *(const bf16x8*)(&Vt[ct * 16 + t][32 + quad * 8]);
            o[ct] = __builtin_amdgcn_mfma_f32_16x16x32_bf16(ap0, bv0, o[ct], 0, 0, 0);
            o[ct] = __builtin_amdgcn_mfma_f32_16x16x32_bf16(ap1, bv1, o[ct], 0, 0, 0);
        }
    }

    // epilogue: divide by l (per q-row) and store
    float rinv[4];
#pragma unroll
    for (int r = 0; r < 4; ++r) rinv[r] = 1.0f / __shfl(lrun, quad * 4 + r, 64);
    const int orow_base = qt * 64 + wave * 16 + quad * 4;
#pragma unroll
    for (int ct = 0; ct < 4; ++ct)
#pragma unroll
        for (int r = 0; r < 4; ++r) {
            size_t row = (size_t)b * Nseq + orow_base + r;
            ctx[row * Dmod + h * DHd + ct * 16 + t] = (__bf16)(o[ct][r] * rinv[r]);
        }
}

// ---------------- SwiGLU ----------------
__global__ __launch_bounds__(256) void swiglu_kernel(
    const __bf16* __restrict__ hpre, __bf16* __restrict__ out)
{
    int idx = blockIdx.x * 256 + threadIdx.x;
    if (idx >= ROWS * HPAD) return;
    int r = idx / HPAD, c = idx - r * HPAD;
    float v = 0.0f;
    if (c < HHALF) {
        float a  = (float)hpre[(size_t)r * HID + c];
        float b2 = (float)hpre[(size_t)r * HID + HHALF + c];
        v = a / (1.0f + __expf(-a)) * b2;
    }
    out[idx] = (__bf16)v;
}

// ---------------- launch ----------------
extern "C" void kernel_launch(void* const* d_in, const int* in_sizes, int n_in,
                              void* d_out, int out_size, void* d_ws, size_t ws_size,
                              hipStream_t stream)
{
    (void)in_sizes; (void)n_in; (void)out_size; (void)ws_size;
    const float* x      = (const float*)d_in[0];
    const float* coords = (const float*)d_in[1];
    const float* q_w    = (const float*)d_in[2];
    const float* q_b    = (const float*)d_in[3];
    const float* k_w    = (const float*)d_in[4];
    const float* k_b    = (const float*)d_in[5];
    const float* v_w    = (const float*)d_in[6];
    const float* v_b    = (const float*)d_in[7];
    const float* o_w    = (const float*)d_in[8];
    const float* o_b    = (const float*)d_in[9];
    const float* gamma1 = (const float*)d_in[10];
    const float* ln1_w  = (const float*)d_in[11];
    const float* ln1_b  = (const float*)d_in[12];
    const float* fc1_w  = (const float*)d_in[13];
    const float* fc1_b  = (const float*)d_in[14];
    const float* fc2_w  = (const float*)d_in[15];
    const float* fc2_b  = (const float*)d_in[16];
    const float* gamma2 = (const float*)d_in[17];
    const float* ln2_w  = (const float*)d_in[18];
    const float* ln2_b  = (const float*)d_in[19];

    size_t off = 0;
    auto alloc = [&](size_t bytes) {
        void* p = (char*)d_ws + off;
        off += (bytes + 255) & ~(size_t)255;
        return p;
    };
    __bf16* xn    = (__bf16*)alloc((size_t)ROWS * Dmod * 2);
    __bf16* xn2   = (__bf16*)alloc((size_t)ROWS * Dmod * 2);
    __bf16* wqkv  = (__bf16*)alloc((size_t)3 * Dmod * Dmod * 2);
    __bf16* wo    = (__bf16*)alloc((size_t)Dmod * Dmod * 2);
    __bf16* wfc1  = (__bf16*)alloc((size_t)HID * Dmod * 2);
    __bf16* wfc2  = (__bf16*)alloc((size_t)Dmod * HPAD * 2);
    __bf16* qkb   = (__bf16*)alloc((size_t)ROWS * 1024 * 2);
    __bf16* vtg   = (__bf16*)alloc((size_t)Bdim * Hn * DHd * Nseq * 2);
    __bf16* ctxb  = (__bf16*)alloc((size_t)ROWS * Dmod * 2);
    float*  x1    = (float*)alloc((size_t)ROWS * Dmod * 4);
    __bf16* hpre  = (__bf16*)alloc((size_t)ROWS * HID * 2);
    __bf16* hcomb = (__bf16*)alloc((size_t)ROWS * HPAD * 2);

    // weight conversions (q,k,v into one contiguous wqkv)
    convert_pad_kernel<<<(Dmod * Dmod + 255) / 256, 256, 0, stream>>>(q_w, wqkv, Dmod, Dmod, Dmod, Dmod * Dmod);
    convert_pad_kernel<<<(Dmod * Dmod + 255) / 256, 256, 0, stream>>>(k_w, wqkv + (size_t)Dmod * Dmod, Dmod, Dmod, Dmod, Dmod * Dmod);
    convert_pad_kernel<<<(Dmod * Dmod + 255) / 256, 256, 0, stream>>>(v_w, wqkv + (size_t)2 * Dmod * Dmod, Dmod, Dmod, Dmod, Dmod * Dmod);
    convert_pad_kernel<<<(Dmod * Dmod + 255) / 256, 256, 0, stream>>>(o_w, wo, Dmod, Dmod, Dmod, Dmod * Dmod);
    convert_pad_kernel<<<(HID * Dmod + 255) / 256, 256, 0, stream>>>(fc1_w, wfc1, HID, Dmod, Dmod, HID * Dmod);
    convert_pad_kernel<<<(Dmod * HPAD + 255) / 256, 256, 0, stream>>>(fc2_w, wfc2, Dmod, HHALF, HPAD, Dmod * HPAD);

    // LN1
    ln_kernel<<<ROWS, 256, 0, stream>>>(x, ln1_w, ln1_b, xn);

    // fused QKV (V written transposed)
    qkv_gemm<<<dim3(ROWS / 64, 12), 256, 0, stream>>>(xn, wqkv, q_b, k_b, v_b, qkb, vtg);

    // attention
    attn_kernel<<<dim3(Nseq / 64, Hn, Bdim), 256, 0, stream>>>(qkb, vtg, coords, ctxb);

    // O projection + residual1 -> x1 (fp32)
    gemm_bt<1, 64><<<dim3(ROWS / 64, 8), 256, 0, stream>>>(ctxb, Dmod, wo, Dmod, o_b, Dmod, Dmod, nullptr, Dmod, x1, x, gamma1);

    // LN2
    ln_kernel<<<ROWS, 256, 0, stream>>>(x1, ln2_w, ln2_b, xn2);

    // fc1 -> hpre
    gemm_bt<0, 128><<<dim3(ROWS / 64, (HID + 127) / 128), 256, 0, stream>>>(xn2, Dmod, wfc1, Dmod, fc1_b, HID, Dmod, hpre, HID, nullptr, nullptr, nullptr);

    // SwiGLU -> hcomb (padded K)
    swiglu_kernel<<<(ROWS * HPAD + 255) / 256, 256, 0, stream>>>(hpre, hcomb);

    // fc2 + residual2 -> d_out (fp32)
    gemm_bt<1, 64><<<dim3(ROWS / 64, 8), 256, 0, stream>>>(hcomb, HPAD, wfc2, HPAD, fc2_b, Dmod, HPAD, nullptr, Dmod, (float*)d_out, x1, gamma2);
}

// Round 4
// 261.543 us; speedup vs baseline: 1.4141x; 1.1822x over previous
//
#include <hip/hip_runtime.h>
#include <math.h>

#define Bdim  2
#define Nseq  2048
#define Dmod  512
#define Hn    8
#define DHd   64
#define HID   2730
#define HHALF 1365
#define HC    1408      // combined hidden, padded (22*64)
#define NPACK 2816      // packed fc1 output cols (2*HC)
#define ROWS  4096      // Bdim*Nseq

typedef __bf16 bf16x8 __attribute__((ext_vector_type(8)));
typedef __bf16 bf16x4 __attribute__((ext_vector_type(4)));
typedef float  f32x4  __attribute__((ext_vector_type(4)));

__device__ __forceinline__ void glds16(const __bf16* g, __bf16* l) {
    __builtin_amdgcn_global_load_lds(
        (const __attribute__((address_space(1))) void*)g,
        (__attribute__((address_space(3))) void*)l, 16, 0, 0);
}

// ---------------- fused weight conversion: all weights in one launch ----------------
// seg0: wqkv [1536][512]  (q|k|v rows)
// seg1: wo   [512][512]
// seg2: wfc1p [NPACK][512]  packed: row n -> j=n>>5,u=n&31; hidx=(j*16+(u&15)) + (u&16?HHALF:0)
// seg3: wfc2p [512][HC]     col k -> fc2_w col k if k<HHALF else 0
#define SEG0 (1536*512)
#define SEG1 (512*512)
#define SEG2 (NPACK*512)
#define SEG3 (512*HC)
__global__ __launch_bounds__(256) void convert_all(
    const float* __restrict__ q_w, const float* __restrict__ k_w,
    const float* __restrict__ v_w, const float* __restrict__ o_w,
    const float* __restrict__ fc1_w, const float* __restrict__ fc2_w,
    __bf16* __restrict__ wqkv, __bf16* __restrict__ wo,
    __bf16* __restrict__ wfc1p, __bf16* __restrict__ wfc2p)
{
    int idx = blockIdx.x * 256 + threadIdx.x;
    if (idx < SEG0) {
        int n = idx >> 9, k = idx & 511;
        float v = (n < 512) ? q_w[n * 512 + k]
                : (n < 1024) ? k_w[(n - 512) * 512 + k]
                : v_w[(n - 1024) * 512 + k];
        wqkv[idx] = (__bf16)v;
        return;
    }
    idx -= SEG0;
    if (idx < SEG1) { wo[idx] = (__bf16)o_w[idx]; return; }
    idx -= SEG1;
    if (idx < SEG2) {
        int n = idx >> 9, k = idx & 511;
        int j = n >> 5, u = n & 31;
        int base = j * 16 + (u & 15);
        float v = 0.0f;
        if (base < HHALF) {
            int hidx = base + ((u & 16) ? HHALF : 0);
            v = fc1_w[(size_t)hidx * 512 + k];
        }
        wfc1p[idx] = (__bf16)v;
        return;
    }
    idx -= SEG2;
    if (idx < SEG3) {
        int n = idx / HC, k = idx - n * HC;
        float v = (k < HHALF) ? fc2_w[(size_t)n * HHALF + k] : 0.0f;
        wfc2p[idx] = (__bf16)v;
    }
}

// ---------------- LayerNorm fp32 -> bf16 (row = 512) ----------------
__global__ __launch_bounds__(256) void ln_kernel(
    const float* __restrict__ x, const float* __restrict__ w,
    const float* __restrict__ b, __bf16* __restrict__ out)
{
    const int row = blockIdx.x;
    const int tid = threadIdx.x;
    const float* xr = x + (size_t)row * Dmod;
    float2 v = *(const float2*)(xr + tid * 2);
    float s  = v.x + v.y;
    float sq = v.x * v.x + v.y * v.y;
#pragma unroll
    for (int m = 1; m < 64; m <<= 1) {
        s  += __shfl_xor(s, m, 64);
        sq += __shfl_xor(sq, m, 64);
    }
    __shared__ float ss[4], ssq[4];
    const int wv = tid >> 6;
    if ((tid & 63) == 0) { ss[wv] = s; ssq[wv] = sq; }
    __syncthreads();
    s  = ss[0] + ss[1] + ss[2] + ss[3];
    sq = ssq[0] + ssq[1] + ssq[2] + ssq[3];
    const float mean = s * (1.0f / Dmod);
    const float var  = sq * (1.0f / Dmod) - mean * mean;
    const float rstd = rsqrtf(var + 1e-5f);
    float2 wv2 = *(const float2*)(w + tid * 2);
    float2 bv2 = *(const float2*)(b + tid * 2);
    __bf16* orow = out + (size_t)row * Dmod + tid * 2;
    orow[0] = (__bf16)((v.x - mean) * rstd * wv2.x + bv2.x);
    orow[1] = (__bf16)((v.y - mean) * rstd * wv2.y + bv2.y);
}

// ---------------- 64xN residual GEMM (o-proj, fc2): out_f32 = res + g*(A·B^T + bias) ----------------
// N fixed 512 per launch geometry (no col guard); register-prefetched staging.
__global__ __launch_bounds__(256) void gemm_res(
    const __bf16* __restrict__ A, int lda,
    const __bf16* __restrict__ Bw, int ldb,
    const float* __restrict__ bias, int K,
    float* __restrict__ out_f32, int ld_out,
    const float* __restrict__ res, const float* __restrict__ g)
{
    __shared__ __bf16 As[64][40];
    __shared__ __bf16 Bs[64][40];
    const int tid  = threadIdx.x;
    const int wave = tid >> 6, lane = tid & 63;
    const int t    = lane & 15, quad = lane >> 4;
    const int m0   = blockIdx.x * 64;
    const int n0   = blockIdx.y * 64;
    const int sr   = tid >> 2, sc = (tid & 3) * 8;

    f32x4 acc[4] = {};
    bf16x8 av = *(const bf16x8*)(A  + (size_t)(m0 + sr) * lda + sc);
    bf16x8 bv = *(const bf16x8*)(Bw + (size_t)(n0 + sr) * ldb + sc);

    for (int k0 = 0; k0 < K; k0 += 32) {
        __syncthreads();
        *(bf16x8*)(&As[sr][sc]) = av;
        *(bf16x8*)(&Bs[sr][sc]) = bv;
        __syncthreads();
        if (k0 + 32 < K) {
            av = *(const bf16x8*)(A  + (size_t)(m0 + sr) * lda + (k0 + 32 + sc));
            bv = *(const bf16x8*)(Bw + (size_t)(n0 + sr) * ldb + (k0 + 32 + sc));
        }
        bf16x8 a = *(const bf16x8*)(&As[wave * 16 + t][quad * 8]);
#pragma unroll
        for (int ct = 0; ct < 4; ++ct) {
            bf16x8 b = *(const bf16x8*)(&Bs[ct * 16 + t][quad * 8]);
            acc[ct] = __builtin_amdgcn_mfma_f32_16x16x32_bf16(a, b, acc[ct], 0, 0, 0);
        }
    }

    const int row_base = m0 + wave * 16 + quad * 4;
#pragma unroll
    for (int ct = 0; ct < 4; ++ct) {
        const int col = n0 + ct * 16 + t;
        const float bb = bias[col];
#pragma unroll
        for (int r = 0; r < 4; ++r) {
            const int row = row_base + r;
            out_f32[(size_t)row * ld_out + col] =
                res[(size_t)row * ld_out + col] + g[col] * (acc[ct][r] + bb);
        }
    }
}

// ---------------- 128x128 QKV GEMM (glds staging); V third written transposed ----------------
__global__ __launch_bounds__(256) void qkv_gemm128(
    const __bf16* __restrict__ A, const __bf16* __restrict__ W,
    const float* __restrict__ qb_, const float* __restrict__ kb_,
    const float* __restrict__ vb_,
    __bf16* __restrict__ qk, __bf16* __restrict__ vtg)
{
    __shared__ __bf16 As[128 * 32];
    __shared__ __bf16 Bs[128 * 32];
    const int tid  = threadIdx.x;
    const int wave = tid >> 6, lane = tid & 63;
    const int t    = lane & 15, quad = lane >> 4;
    const int m0   = blockIdx.x * 128, n0 = blockIdx.y * 128;
    const int mr   = (wave & 1) * 64,  nr = (wave >> 1) * 64;
    const int ra0 = tid >> 2,          ca0 = (tid & 3) * 8;
    const int ra1 = (tid + 256) >> 2,  ca1 = (tid & 3) * 8;

    f32x4 acc[4][4] = {};

    for (int k0 = 0; k0 < Dmod; k0 += 32) {
        __syncthreads();
        glds16(A + (size_t)(m0 + ra0) * Dmod + k0 + ca0, As + tid * 8);
        glds16(A + (size_t)(m0 + ra1) * Dmod + k0 + ca1, As + (tid + 256) * 8);
        glds16(W + (size_t)(n0 + ra0) * Dmod + k0 + ca0, Bs + tid * 8);
        glds16(W + (size_t)(n0 + ra1) * Dmod + k0 + ca1, Bs + (tid + 256) * 8);
        __syncthreads();
        bf16x8 af[4], bfr[4];
#pragma unroll
        for (int mi = 0; mi < 4; ++mi)
            af[mi] = *(const bf16x8*)(As + (mr + mi * 16 + t) * 32 + quad * 8);
#pragma unroll
        for (int ni = 0; ni < 4; ++ni)
            bfr[ni] = *(const bf16x8*)(Bs + (nr + ni * 16 + t) * 32 + quad * 8);
#pragma unroll
        for (int mi = 0; mi < 4; ++mi)
#pragma unroll
            for (int ni = 0; ni < 4; ++ni)
                acc[mi][ni] = __builtin_amdgcn_mfma_f32_16x16x32_bf16(af[mi], bfr[ni], acc[mi][ni], 0, 0, 0);
    }

#pragma unroll
    for (int mi = 0; mi < 4; ++mi) {
        const int row_base = m0 + mr + mi * 16 + quad * 4;
#pragma unroll
        for (int ni = 0; ni < 4; ++ni) {
            const int col = n0 + nr + ni * 16 + t;
            const float bb = (col < 512) ? qb_[col]
                            : (col < 1024) ? kb_[col - 512] : vb_[col - 1024];
            if (col < 1024) {
#pragma unroll
                for (int r = 0; r < 4; ++r)
                    qk[(size_t)(row_base + r) * 1024 + col] = (__bf16)(acc[mi][ni][r] + bb);
            } else {
                const int f = col - 1024, hh = f >> 6, dh = f & 63;
                const int bI = row_base >> 11, n = row_base & 2047;
                bf16x4 pk;
#pragma unroll
                for (int r = 0; r < 4; ++r) pk[r] = (__bf16)(acc[mi][ni][r] + bb);
                *(bf16x4*)(vtg + ((size_t)((bI * 8 + hh) * 64 + dh)) * Nseq + n) = pk;
            }
        }
    }
}

// ---------------- 128x128 fc1 GEMM with fused SwiGLU epilogue ----------------
// B = wfc1p (packed h1/h2 interleaved at 16-col granularity); out = hcomb [ROWS][HC]
__global__ __launch_bounds__(256) void fc1_gemm128(
    const __bf16* __restrict__ A, const __bf16* __restrict__ W,
    const float* __restrict__ fc1_b_, __bf16* __restrict__ out)
{
    __shared__ __bf16 As[128 * 32];
    __shared__ __bf16 Bs[128 * 32];
    const int tid  = threadIdx.x;
    const int wave = tid >> 6, lane = tid & 63;
    const int t    = lane & 15, quad = lane >> 4;
    const int m0   = blockIdx.x * 128, n0 = blockIdx.y * 128;
    const int mr   = (wave & 1) * 64,  nr = (wave >> 1) * 64;
    const int ra0 = tid >> 2,          ca0 = (tid & 3) * 8;
    const int ra1 = (tid + 256) >> 2,  ca1 = (tid & 3) * 8;

    f32x4 acc[4][4] = {};

    for (int k0 = 0; k0 < Dmod; k0 += 32) {
        __syncthreads();
        glds16(A + (size_t)(m0 + ra0) * Dmod + k0 + ca0, As + tid * 8);
        glds16(A + (size_t)(m0 + ra1) * Dmod + k0 + ca1, As + (tid + 256) * 8);
        glds16(W + (size_t)(n0 + ra0) * Dmod + k0 + ca0, Bs + tid * 8);
        glds16(W + (size_t)(n0 + ra1) * Dmod + k0 + ca1, Bs + (tid + 256) * 8);
        __syncthreads();
        bf16x8 af[4], bfr[4];
#pragma unroll
        for (int mi = 0; mi < 4; ++mi)
            af[mi] = *(const bf16x8*)(As + (mr + mi * 16 + t) * 32 + quad * 8);
#pragma unroll
        for (int ni = 0; ni < 4; ++ni)
            bfr[ni] = *(const bf16x8*)(Bs + (nr + ni * 16 + t) * 32 + quad * 8);
#pragma unroll
        for (int mi = 0; mi < 4; ++mi)
#pragma unroll
            for (int ni = 0; ni < 4; ++ni)
                acc[mi][ni] = __builtin_amdgcn_mfma_f32_16x16x32_bf16(af[mi], bfr[ni], acc[mi][ni], 0, 0, 0);
    }

    // epilogue: ni even = h1, ni odd = h2 of the same 16 hidden cols
#pragma unroll
    for (int mi = 0; mi < 4; ++mi) {
        const int row_base = m0 + mr + mi * 16 + quad * 4;
#pragma unroll
        for (int gI = 0; gI < 2; ++gI) {
            const int base = n0 + nr + gI * 32;
            const int hb = (base >> 5) * 16 + t;       // combined col == h index
            const bool valid = hb < HHALF;
            const float b1 = valid ? fc1_b_[hb] : 0.0f;
            const float b2 = valid ? fc1_b_[HHALF + hb] : 0.0f;
#pragma unroll
            for (int r = 0; r < 4; ++r) {
                float a = acc[mi][2 * gI][r] + b1;
                float c = acc[mi][2 * gI + 1][r] + b2;
                float sw = a / (1.0f + __expf(-a)) * c;
                out[(size_t)(row_base + r) * HC + hb] = (__bf16)sw;
            }
        }
    }
}

// ---------------- Flash attention, S^T formulation, no-max softmax, prefetched ----------------
__global__ __launch_bounds__(256) void attn_kernel(
    const __bf16* __restrict__ qk, const __bf16* __restrict__ vt,
    const float* __restrict__ coords, __bf16* __restrict__ ctx)
{
    constexpr int LD = 72;
    __shared__ __bf16 Ks[64][LD];
    __shared__ __bf16 Vt[64][LD];   // Vt[dh][key]
    __shared__ __bf16 Ps[64][LD];   // wave-private rows
    __shared__ float2 kco[64];

    const int qt = blockIdx.x, h = blockIdx.y, b = blockIdx.z;
    const int bh = b * Hn + h;
    const int tid = threadIdx.x;
    const int wave = tid >> 6, lane = tid & 63;
    const int t = lane & 15, quad = lane >> 4;
    const float c1 = 0.125f * 1.44269504f;                  // scale * log2(e)
    const float d1 = exp2f(-(float)(h + 1)) * 1.44269504f;  // slope * log2(e)

    // Q fragments direct from global (B-operand: Q[q=t][dh=quad*8+j])
    const int qrow = qt * 64 + wave * 16 + t;
    const size_t qbase = (size_t)(b * Nseq + qrow) * 1024 + h * DHd;
    bf16x8 bq0 = *(const bf16x8*)(qk + qbase + quad * 8);
    bf16x8 bq1 = *(const bf16x8*)(qk + qbase + 32 + quad * 8);
    float2 qc = *(const float2*)(coords + (size_t)(b * Nseq + qrow) * 2);
    const float qx = qc.x, qy = qc.y;

    const int sr = tid >> 3, scc = (tid & 7) * 8;
    const __bf16* kbase = qk + (size_t)(b * Nseq) * 1024 + 512 + h * DHd;
    const __bf16* vbase = vt + (size_t)(bh * 64) * Nseq;

    bf16x8 kreg0, kreg1, vreg0, vreg1;
    float2 kcreg = {0.f, 0.f};
    kreg0 = *(const bf16x8*)(kbase + (size_t)sr * 1024 + scc);
    kreg1 = *(const bf16x8*)(kbase + (size_t)(sr + 32) * 1024 + scc);
    vreg0 = *(const bf16x8*)(vbase + (size_t)sr * Nseq + scc);
    vreg1 = *(const bf16x8*)(vbase + (size_t)(sr + 32) * Nseq + scc);
    if (tid < 64) kcreg = *(const float2*)(coords + (size_t)(b * Nseq + tid) * 2);

    f32x4 o[4] = {};
    float lrun = 0.0f;

    for (int kt = 0; kt < Nseq / 64; ++kt) {
        __syncthreads();                 // prev iteration's LDS consumers done
        *(bf16x8*)(&Ks[sr][scc])      = kreg0;
        *(bf16x8*)(&Ks[sr + 32][scc]) = kreg1;
        *(bf16x8*)(&Vt[sr][scc])      = vreg0;
        *(bf16x8*)(&Vt[sr + 32][scc]) = vreg1;
        if (tid < 64) kco[tid] = kcreg;
        __syncthreads();
        if (kt + 1 < Nseq / 64) {        // prefetch next tile (overlaps compute)
            const int kn = (kt + 1) * 64;
            kreg0 = *(const bf16x8*)(kbase + (size_t)(kn + sr) * 1024 + scc);
            kreg1 = *(const bf16x8*)(kbase + (size_t)(kn + sr + 32) * 1024 + scc);
            vreg0 = *(const bf16x8*)(vbase + (size_t)sr * Nseq + kn + scc);
            vreg1 = *(const bf16x8*)(vbase + (size_t)(sr + 32) * Nseq + kn + scc);
            if (tid < 64) kcreg = *(const float2*)(coords + (size_t)(b * Nseq + kn + tid) * 2);
        }

        // S^T = K·Q^T : rows key=am*16+quad*4+r, col q=t
        f32x4 s[4];
#pragma unroll
        for (int am = 0; am < 4; ++am) {
            bf16x8 a0 = *(const bf16x8*)(&Ks[am * 16 + t][quad * 8]);
            bf16x8 a1 = *(const bf16x8*)(&Ks[am * 16 + t][32 + quad * 8]);
            f32x4 z = {};
            z = __builtin_amdgcn_mfma_f32_16x16x32_bf16(a0, bq0, z, 0, 0, 0);
            s[am] = __builtin_amdgcn_mfma_f32_16x16x32_bf16(a1, bq1, z, 0, 0, 0);
        }

        // p = exp2(c1*s - d1*dist); accumulate l per-lane (no max, no rescale)
        float p[4][4];
#pragma unroll
        for (int am = 0; am < 4; ++am)
#pragma unroll
            for (int r = 0; r < 4; ++r) {
                float2 kc = kco[am * 16 + quad * 4 + r];
                float dx = qx - kc.x, dy = qy - kc.y;
                float e = exp2f(s[am][r] * c1 - d1 * sqrtf(dx * dx + dy * dy));
                p[am][r] = e;
                lrun += e;
            }

        // P -> LDS (wave-private rows, packed b64)
#pragma unroll
        for (int am = 0; am < 4; ++am) {
            bf16x4 pk;
#pragma unroll
            for (int r = 0; r < 4; ++r) pk[r] = (__bf16)p[am][r];
            *(bf16x4*)(&Ps[wave * 16 + t][am * 16 + quad * 4]) = pk;
        }

        bf16x8 ap0 = *(const bf16x8*)(&Ps[wave * 16 + t][quad * 8]);
        bf16x8 ap1 = *(const bf16x8*)(&Ps[wave * 16 + t][32 + quad * 8]);
#pragma unroll
        for (int ct = 0; ct < 4; ++ct) {
            bf16x8 bv0 = *(const bf16x8*)(&Vt[ct * 16 + t][quad * 8]);
            bf16x8 bv1 = *(const bf16x8*)(&Vt[ct * 16 + t][32 + quad * 8]);
            o[ct] = __builtin_amdgcn_mfma_f32_16x16x32_bf16(ap0, bv0, o[ct], 0, 0, 0);
            o[ct] = __builtin_amdgcn_mfma_f32_16x16x32_bf16(ap1, bv1, o[ct], 0, 0, 0);
        }
    }

    // epilogue: reduce l across quads, divide, store
    lrun += __shfl_xor(lrun, 16, 64);
    lrun += __shfl_xor(lrun, 32, 64);
    float rinv[4];
#pragma unroll
    for (int r = 0; r < 4; ++r) rinv[r] = 1.0f / __shfl(lrun, quad * 4 + r, 64);
    const int orow_base = qt * 64 + wave * 16 + quad * 4;
#pragma unroll
    for (int ct = 0; ct < 4; ++ct)
#pragma unroll
        for (int r = 0; r < 4; ++r) {
            size_t row = (size_t)b * Nseq + orow_base + r;
            ctx[row * Dmod + h * DHd + ct * 16 + t] = (__bf16)(o[ct][r] * rinv[r]);
        }
}

// ---------------- launch ----------------
extern "C" void kernel_launch(void* const* d_in, const int* in_sizes, int n_in,
                              void* d_out, int out_size, void* d_ws, size_t ws_size,
                              hipStream_t stream)
{
    (void)in_sizes; (void)n_in; (void)out_size; (void)ws_size;
    const float* x      = (const float*)d_in[0];
    const float* coords = (const float*)d_in[1];
    const float* q_w    = (const float*)d_in[2];
    const float* q_b    = (const float*)d_in[3];
    const float* k_w    = (const float*)d_in[4];
    const float* k_b    = (const float*)d_in[5];
    const float* v_w    = (const float*)d_in[6];
    const float* v_b    = (const float*)d_in[7];
    const float* o_w    = (const float*)d_in[8];
    const float* o_b    = (const float*)d_in[9];
    const float* gamma1 = (const float*)d_in[10];
    const float* ln1_w  = (const float*)d_in[11];
    const float* ln1_b  = (const float*)d_in[12];
    const float* fc1_w  = (const float*)d_in[13];
    const float* fc1_b  = (const float*)d_in[14];
    const float* fc2_w  = (const float*)d_in[15];
    const float* fc2_b  = (const float*)d_in[16];
    const float* gamma2 = (const float*)d_in[17];
    const float* ln2_w  = (const float*)d_in[18];
    const float* ln2_b  = (const float*)d_in[19];

    size_t off = 0;
    auto alloc = [&](size_t bytes) {
        void* p = (char*)d_ws + off;
        off += (bytes + 255) & ~(size_t)255;
        return p;
    };
    __bf16* wqkv  = (__bf16*)alloc((size_t)1536 * 512 * 2);
    __bf16* wo    = (__bf16*)alloc((size_t)512 * 512 * 2);
    __bf16* wfc1p = (__bf16*)alloc((size_t)NPACK * 512 * 2);
    __bf16* wfc2p = (__bf16*)alloc((size_t)512 * HC * 2);
    __bf16* xn    = (__bf16*)alloc((size_t)ROWS * Dmod * 2);
    __bf16* xn2   = (__bf16*)alloc((size_t)ROWS * Dmod * 2);
    __bf16* qkb   = (__bf16*)alloc((size_t)ROWS * 1024 * 2);
    __bf16* vtg   = (__bf16*)alloc((size_t)Bdim * Hn * DHd * Nseq * 2);
    __bf16* ctxb  = (__bf16*)alloc((size_t)ROWS * Dmod * 2);
    float*  x1    = (float*)alloc((size_t)ROWS * Dmod * 4);
    __bf16* hcomb = (__bf16*)alloc((size_t)ROWS * HC * 2);

    // all weight conversions, one launch
    const int conv_total = SEG0 + SEG1 + SEG2 + SEG3;
    convert_all<<<(conv_total + 255) / 256, 256, 0, stream>>>(
        q_w, k_w, v_w, o_w, fc1_w, fc2_w, wqkv, wo, wfc1p, wfc2p);

    // LN1
    ln_kernel<<<ROWS, 256, 0, stream>>>(x, ln1_w, ln1_b, xn);

    // fused QKV (V written transposed), 128x128 tiles
    qkv_gemm128<<<dim3(ROWS / 128, 12), 256, 0, stream>>>(xn, wqkv, q_b, k_b, v_b, qkb, vtg);

    // attention
    attn_kernel<<<dim3(Nseq / 64, Hn, Bdim), 256, 0, stream>>>(qkb, vtg, coords, ctxb);

    // O projection + residual1 -> x1 (fp32)
    gemm_res<<<dim3(ROWS / 64, Dmod / 64), 256, 0, stream>>>(
        ctxb, Dmod, wo, Dmod, o_b, Dmod, x1, Dmod, x, gamma1);

    // LN2
    ln_kernel<<<ROWS, 256, 0, stream>>>(x1, ln2_w, ln2_b, xn2);

    // fc1 + fused SwiGLU -> hcomb [ROWS][HC]
    fc1_gemm128<<<dim3(ROWS / 128, NPACK / 128), 256, 0, stream>>>(xn2, wfc1p, fc1_b, hcomb);

    // fc2 + residual2 -> d_out (fp32)
    gemm_res<<<dim3(ROWS / 64, Dmod / 64), 256, 0, stream>>>(
        hcomb, HC, wfc2p, HC, fc2_b, HC, (float*)d_out, Dmod, x1, gamma2);
}

// Round 5
// 229.802 us; speedup vs baseline: 1.6094x; 1.1381x over previous
//
#include <hip/hip_runtime.h>
#include <math.h>

#define Bdim  2
#define Nseq  2048
#define Dmod  512
#define Hn    8
#define DHd   64
#define HID   2730
#define HHALF 1365
#define HC    1408      // combined hidden, padded (22*64)
#define NPACK 2816      // packed fc1 output cols (2*HC)
#define ROWS  4096      // Bdim*Nseq
#define NSPLIT 2        // attention split-K factor
#define KT_PER (Nseq / 64 / NSPLIT)   // 16 key-tiles per split

typedef __bf16 bf16x8 __attribute__((ext_vector_type(8)));
typedef __bf16 bf16x4 __attribute__((ext_vector_type(4)));
typedef float  f32x4  __attribute__((ext_vector_type(4)));

__device__ __forceinline__ void glds16(const __bf16* g, __bf16* l) {
    __builtin_amdgcn_global_load_lds(
        (const __attribute__((address_space(1))) void*)g,
        (__attribute__((address_space(3))) void*)l, 16, 0, 0);
}

// ---------------- fused weight conversion: all weights in one launch ----------------
#define SEG0 (1536*512)
#define SEG1 (512*512)
#define SEG2 (NPACK*512)
#define SEG3 (512*HC)
__global__ __launch_bounds__(256) void convert_all(
    const float* __restrict__ q_w, const float* __restrict__ k_w,
    const float* __restrict__ v_w, const float* __restrict__ o_w,
    const float* __restrict__ fc1_w, const float* __restrict__ fc2_w,
    __bf16* __restrict__ wqkv, __bf16* __restrict__ wo,
    __bf16* __restrict__ wfc1p, __bf16* __restrict__ wfc2p)
{
    int idx = blockIdx.x * 256 + threadIdx.x;
    if (idx < SEG0) {
        int n = idx >> 9, k = idx & 511;
        float v = (n < 512) ? q_w[n * 512 + k]
                : (n < 1024) ? k_w[(n - 512) * 512 + k]
                : v_w[(n - 1024) * 512 + k];
        wqkv[idx] = (__bf16)v;
        return;
    }
    idx -= SEG0;
    if (idx < SEG1) { wo[idx] = (__bf16)o_w[idx]; return; }
    idx -= SEG1;
    if (idx < SEG2) {
        int n = idx >> 9, k = idx & 511;
        int j = n >> 5, u = n & 31;
        int base = j * 16 + (u & 15);
        float v = 0.0f;
        if (base < HHALF) {
            int hidx = base + ((u & 16) ? HHALF : 0);
            v = fc1_w[(size_t)hidx * 512 + k];
        }
        wfc1p[idx] = (__bf16)v;
        return;
    }
    idx -= SEG2;
    if (idx < SEG3) {
        int n = idx / HC, k = idx - n * HC;
        float v = (k < HHALF) ? fc2_w[(size_t)n * HHALF + k] : 0.0f;
        wfc2p[idx] = (__bf16)v;
    }
}

// ---------------- LayerNorm fp32 -> bf16 (row = 512) ----------------
__global__ __launch_bounds__(256) void ln_kernel(
    const float* __restrict__ x, const float* __restrict__ w,
    const float* __restrict__ b, __bf16* __restrict__ out)
{
    const int row = blockIdx.x;
    const int tid = threadIdx.x;
    const float* xr = x + (size_t)row * Dmod;
    float2 v = *(const float2*)(xr + tid * 2);
    float s  = v.x + v.y;
    float sq = v.x * v.x + v.y * v.y;
#pragma unroll
    for (int m = 1; m < 64; m <<= 1) {
        s  += __shfl_xor(s, m, 64);
        sq += __shfl_xor(sq, m, 64);
    }
    __shared__ float ss[4], ssq[4];
    const int wv = tid >> 6;
    if ((tid & 63) == 0) { ss[wv] = s; ssq[wv] = sq; }
    __syncthreads();
    s  = ss[0] + ss[1] + ss[2] + ss[3];
    sq = ssq[0] + ssq[1] + ssq[2] + ssq[3];
    const float mean = s * (1.0f / Dmod);
    const float var  = sq * (1.0f / Dmod) - mean * mean;
    const float rstd = rsqrtf(var + 1e-5f);
    float2 wv2 = *(const float2*)(w + tid * 2);
    float2 bv2 = *(const float2*)(b + tid * 2);
    __bf16* orow = out + (size_t)row * Dmod + tid * 2;
    orow[0] = (__bf16)((v.x - mean) * rstd * wv2.x + bv2.x);
    orow[1] = (__bf16)((v.y - mean) * rstd * wv2.y + bv2.y);
}

// ---------------- 64xN residual GEMM: out_f32 = res + g*(A·B^T + bias) ----------------
__global__ __launch_bounds__(256) void gemm_res(
    const __bf16* __restrict__ A, int lda,
    const __bf16* __restrict__ Bw, int ldb,
    const float* __restrict__ bias, int K,
    float* __restrict__ out_f32, int ld_out,
    const float* __restrict__ res, const float* __restrict__ g)
{
    __shared__ __bf16 As[64][40];
    __shared__ __bf16 Bs[64][40];
    const int tid  = threadIdx.x;
    const int wave = tid >> 6, lane = tid & 63;
    const int t    = lane & 15, quad = lane >> 4;
    const int m0   = blockIdx.x * 64;
    const int n0   = blockIdx.y * 64;
    const int sr   = tid >> 2, sc = (tid & 3) * 8;

    f32x4 acc[4] = {};
    bf16x8 av = *(const bf16x8*)(A  + (size_t)(m0 + sr) * lda + sc);
    bf16x8 bv = *(const bf16x8*)(Bw + (size_t)(n0 + sr) * ldb + sc);

    for (int k0 = 0; k0 < K; k0 += 32) {
        __syncthreads();
        *(bf16x8*)(&As[sr][sc]) = av;
        *(bf16x8*)(&Bs[sr][sc]) = bv;
        __syncthreads();
        if (k0 + 32 < K) {
            av = *(const bf16x8*)(A  + (size_t)(m0 + sr) * lda + (k0 + 32 + sc));
            bv = *(const bf16x8*)(Bw + (size_t)(n0 + sr) * ldb + (k0 + 32 + sc));
        }
        bf16x8 a = *(const bf16x8*)(&As[wave * 16 + t][quad * 8]);
#pragma unroll
        for (int ct = 0; ct < 4; ++ct) {
            bf16x8 b = *(const bf16x8*)(&Bs[ct * 16 + t][quad * 8]);
            acc[ct] = __builtin_amdgcn_mfma_f32_16x16x32_bf16(a, b, acc[ct], 0, 0, 0);
        }
    }

    const int row_base = m0 + wave * 16 + quad * 4;
#pragma unroll
    for (int ct = 0; ct < 4; ++ct) {
        const int col = n0 + ct * 16 + t;
        const float bb = bias[col];
#pragma unroll
        for (int r = 0; r < 4; ++r) {
            const int row = row_base + r;
            out_f32[(size_t)row * ld_out + col] =
                res[(size_t)row * ld_out + col] + g[col] * (acc[ct][r] + bb);
        }
    }
}

// ---------------- 128x128 QKV GEMM (glds staging); V third written transposed ----------------
__global__ __launch_bounds__(256) void qkv_gemm128(
    const __bf16* __restrict__ A, const __bf16* __restrict__ W,
    const float* __restrict__ qb_, const float* __restrict__ kb_,
    const float* __restrict__ vb_,
    __bf16* __restrict__ qk, __bf16* __restrict__ vtg)
{
    __shared__ __bf16 As[128 * 32];
    __shared__ __bf16 Bs[128 * 32];
    const int tid  = threadIdx.x;
    const int wave = tid >> 6, lane = tid & 63;
    const int t    = lane & 15, quad = lane >> 4;
    const int m0   = blockIdx.x * 128, n0 = blockIdx.y * 128;
    const int mr   = (wave & 1) * 64,  nr = (wave >> 1) * 64;
    const int ra0 = tid >> 2,          ca0 = (tid & 3) * 8;
    const int ra1 = (tid + 256) >> 2,  ca1 = (tid & 3) * 8;

    f32x4 acc[4][4] = {};

    for (int k0 = 0; k0 < Dmod; k0 += 32) {
        __syncthreads();
        glds16(A + (size_t)(m0 + ra0) * Dmod + k0 + ca0, As + tid * 8);
        glds16(A + (size_t)(m0 + ra1) * Dmod + k0 + ca1, As + (tid + 256) * 8);
        glds16(W + (size_t)(n0 + ra0) * Dmod + k0 + ca0, Bs + tid * 8);
        glds16(W + (size_t)(n0 + ra1) * Dmod + k0 + ca1, Bs + (tid + 256) * 8);
        __syncthreads();
        bf16x8 af[4], bfr[4];
#pragma unroll
        for (int mi = 0; mi < 4; ++mi)
            af[mi] = *(const bf16x8*)(As + (mr + mi * 16 + t) * 32 + quad * 8);
#pragma unroll
        for (int ni = 0; ni < 4; ++ni)
            bfr[ni] = *(const bf16x8*)(Bs + (nr + ni * 16 + t) * 32 + quad * 8);
#pragma unroll
        for (int mi = 0; mi < 4; ++mi)
#pragma unroll
            for (int ni = 0; ni < 4; ++ni)
                acc[mi][ni] = __builtin_amdgcn_mfma_f32_16x16x32_bf16(af[mi], bfr[ni], acc[mi][ni], 0, 0, 0);
    }

#pragma unroll
    for (int mi = 0; mi < 4; ++mi) {
        const int row_base = m0 + mr + mi * 16 + quad * 4;
#pragma unroll
        for (int ni = 0; ni < 4; ++ni) {
            const int col = n0 + nr + ni * 16 + t;
            const float bb = (col < 512) ? qb_[col]
                            : (col < 1024) ? kb_[col - 512] : vb_[col - 1024];
            if (col < 1024) {
#pragma unroll
                for (int r = 0; r < 4; ++r)
                    qk[(size_t)(row_base + r) * 1024 + col] = (__bf16)(acc[mi][ni][r] + bb);
            } else {
                const int f = col - 1024, hh = f >> 6, dh = f & 63;
                const int bI = row_base >> 11, n = row_base & 2047;
                bf16x4 pk;
#pragma unroll
                for (int r = 0; r < 4; ++r) pk[r] = (__bf16)(acc[mi][ni][r] + bb);
                *(bf16x4*)(vtg + ((size_t)((bI * 8 + hh) * 64 + dh)) * Nseq + n) = pk;
            }
        }
    }
}

// ---------------- 128x128 fc1 GEMM with fused SwiGLU epilogue ----------------
__global__ __launch_bounds__(256) void fc1_gemm128(
    const __bf16* __restrict__ A, const __bf16* __restrict__ W,
    const float* __restrict__ fc1_b_, __bf16* __restrict__ out)
{
    __shared__ __bf16 As[128 * 32];
    __shared__ __bf16 Bs[128 * 32];
    const int tid  = threadIdx.x;
    const int wave = tid >> 6, lane = tid & 63;
    const int t    = lane & 15, quad = lane >> 4;
    const int m0   = blockIdx.x * 128, n0 = blockIdx.y * 128;
    const int mr   = (wave & 1) * 64,  nr = (wave >> 1) * 64;
    const int ra0 = tid >> 2,          ca0 = (tid & 3) * 8;
    const int ra1 = (tid + 256) >> 2,  ca1 = (tid & 3) * 8;

    f32x4 acc[4][4] = {};

    for (int k0 = 0; k0 < Dmod; k0 += 32) {
        __syncthreads();
        glds16(A + (size_t)(m0 + ra0) * Dmod + k0 + ca0, As + tid * 8);
        glds16(A + (size_t)(m0 + ra1) * Dmod + k0 + ca1, As + (tid + 256) * 8);
        glds16(W + (size_t)(n0 + ra0) * Dmod + k0 + ca0, Bs + tid * 8);
        glds16(W + (size_t)(n0 + ra1) * Dmod + k0 + ca1, Bs + (tid + 256) * 8);
        __syncthreads();
        bf16x8 af[4], bfr[4];
#pragma unroll
        for (int mi = 0; mi < 4; ++mi)
            af[mi] = *(const bf16x8*)(As + (mr + mi * 16 + t) * 32 + quad * 8);
#pragma unroll
        for (int ni = 0; ni < 4; ++ni)
            bfr[ni] = *(const bf16x8*)(Bs + (nr + ni * 16 + t) * 32 + quad * 8);
#pragma unroll
        for (int mi = 0; mi < 4; ++mi)
#pragma unroll
            for (int ni = 0; ni < 4; ++ni)
                acc[mi][ni] = __builtin_amdgcn_mfma_f32_16x16x32_bf16(af[mi], bfr[ni], acc[mi][ni], 0, 0, 0);
    }

#pragma unroll
    for (int mi = 0; mi < 4; ++mi) {
        const int row_base = m0 + mr + mi * 16 + quad * 4;
#pragma unroll
        for (int gI = 0; gI < 2; ++gI) {
            const int base = n0 + nr + gI * 32;
            const int hb = (base >> 5) * 16 + t;
            const bool valid = hb < HHALF;
            const float b1 = valid ? fc1_b_[hb] : 0.0f;
            const float b2 = valid ? fc1_b_[HHALF + hb] : 0.0f;
#pragma unroll
            for (int r = 0; r < 4; ++r) {
                float a = acc[mi][2 * gI][r] + b1;
                float c = acc[mi][2 * gI + 1][r] + b2;
                float sw = a / (1.0f + __expf(-a)) * c;
                out[(size_t)(row_base + r) * HC + hb] = (__bf16)sw;
            }
        }
    }
}

// ---------------- Flash attention, split-K over key tiles, no-max softmax ----------------
// grid: (Nseq/64, Hn, Bdim*NSPLIT); z: s=z>>1, b=z&1. Writes unnormalized fp32
// partial O into op[s] and row-sums into lp[s]; merged by merge_kernel.
__global__ __launch_bounds__(256) void attn_kernel(
    const __bf16* __restrict__ qk, const __bf16* __restrict__ vt,
    const float* __restrict__ coords,
    float* __restrict__ op, float* __restrict__ lp)
{
    constexpr int LD = 72;
    __shared__ __bf16 Ks[64][LD];
    __shared__ __bf16 Vt[64][LD];   // Vt[dh][key]
    __shared__ __bf16 Ps[64][LD];   // wave-private rows
    __shared__ float2 kco[64];

    const int qt = blockIdx.x, h = blockIdx.y;
    const int s = blockIdx.z >> 1, b = blockIdx.z & 1;
    const int bh = b * Hn + h;
    const int tid = threadIdx.x;
    const int wave = tid >> 6, lane = tid & 63;
    const int t = lane & 15, quad = lane >> 4;
    const float c1 = 0.125f * 1.44269504f;                  // scale * log2(e)
    const float d1 = exp2f(-(float)(h + 1)) * 1.44269504f;  // slope * log2(e)
    const int kt0 = s * KT_PER, kt1 = kt0 + KT_PER;

    // Q fragments direct from global (B-operand: Q[q=t][dh=quad*8+j])
    const int qrow = qt * 64 + wave * 16 + t;
    const size_t qbase = (size_t)(b * Nseq + qrow) * 1024 + h * DHd;
    bf16x8 bq0 = *(const bf16x8*)(qk + qbase + quad * 8);
    bf16x8 bq1 = *(const bf16x8*)(qk + qbase + 32 + quad * 8);
    float2 qc = *(const float2*)(coords + (size_t)(b * Nseq + qrow) * 2);
    const float qx = qc.x, qy = qc.y;

    const int sr = tid >> 3, scc = (tid & 7) * 8;
    const __bf16* kbase = qk + (size_t)(b * Nseq) * 1024 + 512 + h * DHd;
    const __bf16* vbase = vt + (size_t)(bh * 64) * Nseq;

    bf16x8 kreg0, kreg1, vreg0, vreg1;
    float2 kcreg = {0.f, 0.f};
    {
        const int kn0 = kt0 * 64;
        kreg0 = *(const bf16x8*)(kbase + (size_t)(kn0 + sr) * 1024 + scc);
        kreg1 = *(const bf16x8*)(kbase + (size_t)(kn0 + sr + 32) * 1024 + scc);
        vreg0 = *(const bf16x8*)(vbase + (size_t)sr * Nseq + kn0 + scc);
        vreg1 = *(const bf16x8*)(vbase + (size_t)(sr + 32) * Nseq + kn0 + scc);
        if (tid < 64) kcreg = *(const float2*)(coords + (size_t)(b * Nseq + kn0 + tid) * 2);
    }

    f32x4 o[4] = {};
    float lrun = 0.0f;

    for (int kt = kt0; kt < kt1; ++kt) {
        __syncthreads();
        *(bf16x8*)(&Ks[sr][scc])      = kreg0;
        *(bf16x8*)(&Ks[sr + 32][scc]) = kreg1;
        *(bf16x8*)(&Vt[sr][scc])      = vreg0;
        *(bf16x8*)(&Vt[sr + 32][scc]) = vreg1;
        if (tid < 64) kco[tid] = kcreg;
        __syncthreads();
        if (kt + 1 < kt1) {              // prefetch next tile
            const int kn = (kt + 1) * 64;
            kreg0 = *(const bf16x8*)(kbase + (size_t)(kn + sr) * 1024 + scc);
            kreg1 = *(const bf16x8*)(kbase + (size_t)(kn + sr + 32) * 1024 + scc);
            vreg0 = *(const bf16x8*)(vbase + (size_t)sr * Nseq + kn + scc);
            vreg1 = *(const bf16x8*)(vbase + (size_t)(sr + 32) * Nseq + kn + scc);
            if (tid < 64) kcreg = *(const float2*)(coords + (size_t)(b * Nseq + kn + tid) * 2);
        }

        // S^T = K·Q^T : rows key=am*16+quad*4+r, col q=t
        f32x4 sA[4];
#pragma unroll
        for (int am = 0; am < 4; ++am) {
            bf16x8 a0 = *(const bf16x8*)(&Ks[am * 16 + t][quad * 8]);
            bf16x8 a1 = *(const bf16x8*)(&Ks[am * 16 + t][32 + quad * 8]);
            f32x4 z = {};
            z = __builtin_amdgcn_mfma_f32_16x16x32_bf16(a0, bq0, z, 0, 0, 0);
            sA[am] = __builtin_amdgcn_mfma_f32_16x16x32_bf16(a1, bq1, z, 0, 0, 0);
        }

        // p = exp2(c1*s - d1*dist); raw transcendental instructions
        float p[4][4];
#pragma unroll
        for (int am = 0; am < 4; ++am)
#pragma unroll
            for (int r = 0; r < 4; ++r) {
                float2 kc = kco[am * 16 + quad * 4 + r];
                float dx = qx - kc.x, dy = qy - kc.y;
                float dist = __builtin_amdgcn_sqrtf(dx * dx + dy * dy);
                float e = __builtin_amdgcn_exp2f(sA[am][r] * c1 - d1 * dist);
                p[am][r] = e;
                lrun += e;
            }

        // P -> LDS (wave-private rows, packed b64)
#pragma unroll
        for (int am = 0; am < 4; ++am) {
            bf16x4 pk;
#pragma unroll
            for (int r = 0; r < 4; ++r) pk[r] = (__bf16)p[am][r];
            *(bf16x4*)(&Ps[wave * 16 + t][am * 16 + quad * 4]) = pk;
        }

        bf16x8 ap0 = *(const bf16x8*)(&Ps[wave * 16 + t][quad * 8]);
        bf16x8 ap1 = *(const bf16x8*)(&Ps[wave * 16 + t][32 + quad * 8]);
#pragma unroll
        for (int ct = 0; ct < 4; ++ct) {
            bf16x8 bv0 = *(const bf16x8*)(&Vt[ct * 16 + t][quad * 8]);
            bf16x8 bv1 = *(const bf16x8*)(&Vt[ct * 16 + t][32 + quad * 8]);
            o[ct] = __builtin_amdgcn_mfma_f32_16x16x32_bf16(ap0, bv0, o[ct], 0, 0, 0);
            o[ct] = __builtin_amdgcn_mfma_f32_16x16x32_bf16(ap1, bv1, o[ct], 0, 0, 0);
        }
    }

    // epilogue: store partial l (per q-row) and unnormalized partial O (fp32)
    lrun += __shfl_xor(lrun, 16, 64);
    lrun += __shfl_xor(lrun, 32, 64);
    if (quad == 0)
        lp[(((size_t)s * Bdim + b) * Hn + h) * Nseq + qt * 64 + wave * 16 + t] = lrun;

    const int orow_base = qt * 64 + wave * 16 + quad * 4;
#pragma unroll
    for (int ct = 0; ct < 4; ++ct)
#pragma unroll
        for (int r = 0; r < 4; ++r) {
            size_t row = (size_t)s * ROWS + b * Nseq + orow_base + r;
            op[row * Dmod + h * DHd + ct * 16 + t] = o[ct][r];
        }
}

// ---------------- merge split-K partials: ctx = (o0+o1)/(l0+l1) ----------------
__global__ __launch_bounds__(256) void merge_kernel(
    const float* __restrict__ op, const float* __restrict__ lp,
    __bf16* __restrict__ ctx)
{
    int idx = blockIdx.x * 256 + threadIdx.x;   // ROWS*128 threads, 4 elems each
    int row = idx >> 7, c4 = (idx & 127) * 4;
    int h = c4 >> 6;
    int b = row >> 11, n = row & 2047;
    float l = lp[(((size_t)0 * Bdim + b) * Hn + h) * Nseq + n]
            + lp[(((size_t)1 * Bdim + b) * Hn + h) * Nseq + n];
    float rl = __builtin_amdgcn_rcpf(l);
    float4 o0 = *(const float4*)(op + (size_t)row * Dmod + c4);
    float4 o1 = *(const float4*)(op + ((size_t)ROWS + row) * Dmod + c4);
    bf16x4 r;
    r[0] = (__bf16)((o0.x + o1.x) * rl);
    r[1] = (__bf16)((o0.y + o1.y) * rl);
    r[2] = (__bf16)((o0.z + o1.z) * rl);
    r[3] = (__bf16)((o0.w + o1.w) * rl);
    *(bf16x4*)(ctx + (size_t)row * Dmod + c4) = r;
}

// ---------------- launch ----------------
extern "C" void kernel_launch(void* const* d_in, const int* in_sizes, int n_in,
                              void* d_out, int out_size, void* d_ws, size_t ws_size,
                              hipStream_t stream)
{
    (void)in_sizes; (void)n_in; (void)out_size; (void)ws_size;
    const float* x      = (const float*)d_in[0];
    const float* coords = (const float*)d_in[1];
    const float* q_w    = (const float*)d_in[2];
    const float* q_b    = (const float*)d_in[3];
    const float* k_w    = (const float*)d_in[4];
    const float* k_b    = (const float*)d_in[5];
    const float* v_w    = (const float*)d_in[6];
    const float* v_b    = (const float*)d_in[7];
    const float* o_w    = (const float*)d_in[8];
    const float* o_b    = (const float*)d_in[9];
    const float* gamma1 = (const float*)d_in[10];
    const float* ln1_w  = (const float*)d_in[11];
    const float* ln1_b  = (const float*)d_in[12];
    const float* fc1_w  = (const float*)d_in[13];
    const float* fc1_b  = (const float*)d_in[14];
    const float* fc2_w  = (const float*)d_in[15];
    const float* fc2_b  = (const float*)d_in[16];
    const float* gamma2 = (const float*)d_in[17];
    const float* ln2_w  = (const float*)d_in[18];
    const float* ln2_b  = (const float*)d_in[19];

    size_t off = 0;
    auto alloc = [&](size_t bytes) {
        void* p = (char*)d_ws + off;
        off += (bytes + 255) & ~(size_t)255;
        return p;
    };
    __bf16* wqkv  = (__bf16*)alloc((size_t)1536 * 512 * 2);
    __bf16* wo    = (__bf16*)alloc((size_t)512 * 512 * 2);
    __bf16* wfc1p = (__bf16*)alloc((size_t)NPACK * 512 * 2);
    __bf16* wfc2p = (__bf16*)alloc((size_t)512 * HC * 2);
    __bf16* xn    = (__bf16*)alloc((size_t)ROWS * Dmod * 2);
    __bf16* xn2   = (__bf16*)alloc((size_t)ROWS * Dmod * 2);
    __bf16* qkb   = (__bf16*)alloc((size_t)ROWS * 1024 * 2);
    __bf16* vtg   = (__bf16*)alloc((size_t)Bdim * Hn * DHd * Nseq * 2);
    __bf16* ctxb  = (__bf16*)alloc((size_t)ROWS * Dmod * 2);
    float*  x1    = (float*)alloc((size_t)ROWS * Dmod * 4);
    __bf16* hcomb = (__bf16*)alloc((size_t)ROWS * HC * 2);
    float*  opb   = (float*)alloc((size_t)NSPLIT * ROWS * Dmod * 4);
    float*  lpb   = (float*)alloc((size_t)NSPLIT * Bdim * Hn * Nseq * 4);

    // all weight conversions, one launch
    const int conv_total = SEG0 + SEG1 + SEG2 + SEG3;
    convert_all<<<(conv_total + 255) / 256, 256, 0, stream>>>(
        q_w, k_w, v_w, o_w, fc1_w, fc2_w, wqkv, wo, wfc1p, wfc2p);

    // LN1
    ln_kernel<<<ROWS, 256, 0, stream>>>(x, ln1_w, ln1_b, xn);

    // fused QKV (V written transposed), 128x128 tiles
    qkv_gemm128<<<dim3(ROWS / 128, 12), 256, 0, stream>>>(xn, wqkv, q_b, k_b, v_b, qkb, vtg);

    // attention (split-K) + merge
    attn_kernel<<<dim3(Nseq / 64, Hn, Bdim * NSPLIT), 256, 0, stream>>>(
        qkb, vtg, coords, opb, lpb);
    merge_kernel<<<(ROWS * 128 + 255) / 256, 256, 0, stream>>>(opb, lpb, ctxb);

    // O projection + residual1 -> x1 (fp32)
    gemm_res<<<dim3(ROWS / 64, Dmod / 64), 256, 0, stream>>>(
        ctxb, Dmod, wo, Dmod, o_b, Dmod, x1, Dmod, x, gamma1);

    // LN2
    ln_kernel<<<ROWS, 256, 0, stream>>>(x1, ln2_w, ln2_b, xn2);

    // fc1 + fused SwiGLU -> hcomb [ROWS][HC]
    fc1_gemm128<<<dim3(ROWS / 128, NPACK / 128), 256, 0, stream>>>(xn2, wfc1p, fc1_b, hcomb);

    // fc2 + residual2 -> d_out (fp32)
    gemm_res<<<dim3(ROWS / 64, Dmod / 64), 256, 0, stream>>>(
        hcomb, HC, wfc2p, HC, fc2_b, HC, (float*)d_out, Dmod, x1, gamma2);
}